// Round 13
// baseline (219.940 us; speedup 1.0000x reference)
//
#include <hip/hip_runtime.h>
#include <hip/hip_bf16.h>

typedef unsigned short u16;
typedef __attribute__((ext_vector_type(8)))  __bf16 bf16x8;
typedef __attribute__((ext_vector_type(8)))  unsigned short u16x8;
typedef __attribute__((ext_vector_type(4)))  unsigned short u16x4;
typedef __attribute__((ext_vector_type(4)))  float f32x4;
typedef __attribute__((ext_vector_type(16))) float f32x16;
typedef __attribute__((ext_vector_type(4)))  unsigned u32x4;

#define MFMA(a, b, c)   __builtin_amdgcn_mfma_f32_16x16x32_bf16((a), (b), (c), 0, 0, 0)
#define MFMA32(a, b, c) __builtin_amdgcn_mfma_f32_32x32x16_bf16((a), (b), (c), 0, 0, 0)

// f32 -> bf16 round-to-nearest-even (bit trick)
__device__ __forceinline__ u16 f2b(float f) {
  union { float f; unsigned u; } x; x.f = f;
  unsigned r = x.u + 0x7fffu + ((x.u >> 16) & 1u);
  return (u16)(r >> 16);
}

__device__ __forceinline__ unsigned pack2(float lo, float hi) {
  const __bf16 a = (__bf16)lo, b = (__bf16)hi;
  return (unsigned)__builtin_bit_cast(u16, a) | ((unsigned)__builtin_bit_cast(u16, b) << 16);
}

// two 8B LDS loads -> one bf16x8 fragment (for 136B-stride rows: 2-way banks, 8B aligned)
__device__ __forceinline__ bf16x8 ld2x64(const u16* p) {
  union { u16x4 h[2]; bf16x8 v; } u;
  u.h[0] = *(const u16x4*)p;
  u.h[1] = *(const u16x4*)(p + 4);
  return u.v;
}

__device__ __forceinline__ void gl_lds16(void* lds, const void* g) {
  __builtin_amdgcn_global_load_lds(
      (const __attribute__((address_space(1))) void*)g,
      (__attribute__((address_space(3))) void*)lds, 16, 0, 0);
}

// ---------------- f32 -> bf16 elementwise ----------------
__global__ __launch_bounds__(256) void cvt_kernel(const float* __restrict__ in,
                                                  u16* __restrict__ out, int n) {
  int i = (blockIdx.x * 256 + threadIdx.x) * 4;
  if (i >= n) return;
  f32x4 v = *(const f32x4*)(in + i);
  u16x4 o;
  o[0] = f2b(v[0]); o[1] = f2b(v[1]); o[2] = f2b(v[2]); o[3] = f2b(v[3]);
  *(u16x4*)(out + i) = o;
}

// ---------------- fused f32 [K=2048][N] -> bf16 [N][K] transposes for all 4 weights ----------
// grid (160, 64): x<64 -> Wq, x<80 -> Wk, x<96 -> Wv, else Wo. One launch instead of four.
__global__ __launch_bounds__(256) void cvt_t_all_kernel(
    const float* __restrict__ Wq, const float* __restrict__ Wk,
    const float* __restrict__ Wv, const float* __restrict__ Wo,
    u16* __restrict__ Wqt, u16* __restrict__ Wkt,
    u16* __restrict__ Wvt, u16* __restrict__ Wot) {
  __shared__ u16 t[32][36];
  const int x = blockIdx.x;
  const float* W; u16* Wt; int N, n0;
  if (x < 64)      { W = Wq; Wt = Wqt; N = 2048; n0 = x * 32; }
  else if (x < 80) { W = Wk; Wt = Wkt; N = 512;  n0 = (x - 64) * 32; }
  else if (x < 96) { W = Wv; Wt = Wvt; N = 512;  n0 = (x - 80) * 32; }
  else             { W = Wo; Wt = Wot; N = 2048; n0 = (x - 96) * 32; }
  const int k0 = blockIdx.y * 32;
  const int r = threadIdx.x >> 3, c4 = (threadIdx.x & 7) * 4;
  f32x4 v = *(const f32x4*)&W[(size_t)(k0 + r) * N + n0 + c4];
  t[c4 + 0][r] = f2b(v[0]);
  t[c4 + 1][r] = f2b(v[1]);
  t[c4 + 2][r] = f2b(v[2]);
  t[c4 + 3][r] = f2b(v[3]);
  __syncthreads();
  u16x4 o;
  o[0] = t[r][c4]; o[1] = t[r][c4 + 1]; o[2] = t[r][c4 + 2]; o[3] = t[r][c4 + 3];
  *(u16x4*)&Wt[(size_t)(n0 + r) * 2048 + k0 + c4] = o;
}

// ---------------- shared GEMM body: C[M=4096][N] = A[4096][2048] @ Bt[N][2048]^T + bias ----------------
// 8-wave / 512-thread variant of the R7-proven 1-phase structure (R12-verified).
template <bool OUT_BF16>
__device__ __forceinline__ void gemm_body(const u16* __restrict__ A, const u16* __restrict__ Bt,
                                          const float* __restrict__ bias, void* __restrict__ C,
                                          const int N, const int n0, const int m0, const float scale) {
  __shared__ __align__(16) u16 As[128 * 32];
  __shared__ __align__(16) u16 Bs[128 * 32];
  const int tid = threadIdx.x;
  const int lane = tid & 63, wv = tid >> 6;
  const int l15 = lane & 15, lg = lane >> 4;
  const int wm = wv >> 2, wn = wv & 3;     // 2 x 4 wave grid
  const int srow = tid >> 2;               // staging row 0..127
  const int g = tid & 3;
  const int gs = g ^ ((srow >> 1) & 3);    // inverse-swizzled source chunk (rule #21)

  f32x4 acc[4][2] = {};

  for (int k0 = 0; k0 < 2048; k0 += 32) {
    gl_lds16(&As[wv << 9], A  + (((size_t)(m0 + srow)) << 11) + k0 + gs * 8);
    gl_lds16(&Bs[wv << 9], Bt + (((size_t)(n0 + srow)) << 11) + k0 + gs * 8);
    __syncthreads();
    bf16x8 af[4], bfr[2];
#pragma unroll
    for (int t = 0; t < 4; t++) {
      const int ra = wm * 64 + t * 16 + l15;
      af[t] = *(const bf16x8*)&As[ra * 32 + ((lg ^ ((ra >> 1) & 3)) << 3)];
    }
#pragma unroll
    for (int u = 0; u < 2; u++) {
      const int rb = wn * 32 + u * 16 + l15;
      bfr[u] = *(const bf16x8*)&Bs[rb * 32 + ((lg ^ ((rb >> 1) & 3)) << 3)];
    }
#pragma unroll
    for (int mt = 0; mt < 4; mt++)
#pragma unroll
      for (int nt = 0; nt < 2; nt++)
        acc[mt][nt] = MFMA(af[mt], bfr[nt], acc[mt][nt]);
    __syncthreads();
  }

#pragma unroll
  for (int nt = 0; nt < 2; nt++) {
    const int col = n0 + wn * 32 + nt * 16 + l15;
    const float bc = bias[col];
#pragma unroll
    for (int mt = 0; mt < 4; mt++) {
#pragma unroll
      for (int r = 0; r < 4; r++) {
        const int row = m0 + wm * 64 + mt * 16 + lg * 4 + r;
        const float v = (acc[mt][nt][r] + bc) * scale;
        if (OUT_BF16) ((u16*)C)[(size_t)row * N + col] = f2b(v);
        else          ((float*)C)[(size_t)row * N + col] = v;
      }
    }
  }
}

// Fused QKV projection. Q is pre-scaled by (1/sqrt(64)) * log2(e) so attention uses exp2.
__global__ __launch_bounds__(512, 6) void qkv_gemm_kernel(
    const u16* __restrict__ xb,
    const u16* __restrict__ Wqt, const u16* __restrict__ Wkt, const u16* __restrict__ Wvt,
    const float* __restrict__ bq, const float* __restrict__ bk, const float* __restrict__ bv,
    u16* __restrict__ Qb, u16* __restrict__ Kb, u16* __restrict__ Vb) {
  const int nb = blockIdx.x;
  const u16* Bt; const float* bias; u16* out; int N, n0; float scale;
  if (nb < 16)      { Bt = Wqt; bias = bq; out = Qb; N = 2048; n0 = nb * 128;        scale = 0.125f * 1.44269504f; }
  else if (nb < 20) { Bt = Wkt; bias = bk; out = Kb; N = 512;  n0 = (nb - 16) * 128; scale = 1.0f; }
  else              { Bt = Wvt; bias = bv; out = Vb; N = 512;  n0 = (nb - 20) * 128; scale = 1.0f; }
  gemm_body<true>(xb, Bt, bias, out, N, n0, blockIdx.y * 128, scale);
}

__global__ __launch_bounds__(512, 6) void oproj_kernel(const u16* __restrict__ Ab,
                                                       const u16* __restrict__ Wot,
                                                       const float* __restrict__ bo,
                                                       float* __restrict__ out) {
  gemm_body<false>(Ab, Wot, bo, out, 2048, blockIdx.x * 128, blockIdx.y * 128, 1.0f);
}

// ---------------- causal GQA flash attention (32x32 swapped-operand, fully in-register P) ----
// grid = 1024 blocks x 256 threads (4 waves = 2 heads x 2 q-halves of 32). Decode: j = i&511;
// hp = j&1 (head-pair), kh = (j>>1)&7, b = (j>>4)&1, p16 = j>>5; qt = i<512 ? 31-p16 : p16.
// 4 blocks/CU (LDS 33.8KB) = 4 independent barrier domains at 16 waves/CU — finer overlap of
// barrier drain vs compute than R12's 2x8-wave blocks. Per-wave compute core UNCHANGED from
// R11/R12 (verified): P exchanged via __shfl_xor(,32)+selects; V^T stride-68; K gl_lds+XOR.
__global__ __launch_bounds__(256, 4) void attn_kernel(const u16* __restrict__ Qb,
                                                      const u16* __restrict__ Kb,
                                                      const u16* __restrict__ Vb,
                                                      u16* __restrict__ Ab) {
  const int i = blockIdx.x;
  const int j = i & 511;
  const int hp = j & 1, kh = (j >> 1) & 7, b = (j >> 4) & 1;
  const int p16 = j >> 5;                       // 0..15
  const int qt = (i < 512) ? (31 - p16) : p16;  // complementary-length pairing

  const int tid = threadIdx.x;
  const int lane = tid & 63, wv = tid >> 6;     // wv 0..3
  const int hh = wv & 1, qh = wv >> 1;          // head-in-pair, q-half
  const int h = kh * 4 + hp * 2 + hh;
  const int l31 = lane & 31, hi = lane >> 5;
  const int swz = (l31 & 7) << 3;

  __shared__ __align__(16) u16 Ks[2][64 * 64];   // K[kv][d ^ ((kv&7)<<3)] (gl_lds, rule #21)
  __shared__ __align__(16) u16 Vt[2][64 * 68];   // V^T[d][kv], stride 68 (2-way banks)

  const u16* Kbase = Kb + (size_t)(b * 2048) * 512 + kh * 64;
  const u16* Vbase = Vb + (size_t)(b * 2048) * 512 + kh * 64;

  const int q0 = qt * 64;

  // Q B-frags: col = q = l31, k = d = c*16 + hi*8 + j
  bf16x8 qf[4];
  {
    const u16* qp = Qb + (size_t)(b * 2048 + q0 + qh * 32 + l31) * 2048 + h * 64 + hi * 8;
#pragma unroll
    for (int c = 0; c < 4; c++) qf[c] = *(const bf16x8*)(qp + c * 16);
  }
  f32x16 ot[2] = {};              // O^T acc: row d = dh*32 + (reg&3)+8*(reg>>2)+4*hi, col q
  float mrow = -30000.0f, srow = 0.f;

  int cur = 0;
  {  // prologue: stage tile 0 into buf 0 (each thread: 2 chunks of K + 2 of V)
#pragma unroll
    for (int s = 0; s < 2; s++) {
      const int cid = s * 256 + tid;            // chunk 0..511
      const int row = cid >> 3, c8 = cid & 7;
      gl_lds16(&Ks[0][s * 2048 + (wv << 9)],
               Kbase + ((size_t)row << 9) + ((c8 ^ (row & 7)) << 3));
      u16x8 vr = *(const u16x8*)(Vbase + ((size_t)row << 9) + c8 * 8);
#pragma unroll
      for (int j8 = 0; j8 < 8; j8++) {
        const int jj = (j8 + c8) & 7;           // rotate so concurrent lanes spread banks
        const int d = c8 * 8 + jj;
        Vt[0][d * 68 + row] = vr[jj];
      }
    }
  }
  for (int it = 0; it <= qt; ++it) {
    __syncthreads();   // buf[cur] fully staged (drains each wave's vmcnt+lgkm, then barrier)
    const bool pre = (it < qt);
    u16x8 vnx[2];
    if (pre) {  // issue next tile's loads early; V LDS-write deferred past compute
#pragma unroll
      for (int s = 0; s < 2; s++) {
        const int cid = s * 256 + tid;
        const int row = cid >> 3, c8 = cid & 7;
        const size_t roff = (size_t)((it + 1) * 64 + row) << 9;
        gl_lds16(&Ks[cur ^ 1][s * 2048 + (wv << 9)],
                 Kbase + roff + ((c8 ^ (row & 7)) << 3));
        vnx[s] = *(const u16x8*)(Vbase + roff + c8 * 8);
      }
    }
    const u16* Kc = Ks[cur];
    const u16* Vc = Vt[cur];

    // S = K Q : sc2[kvh] rows kv = kvh*32 + (reg&3)+8*(reg>>2)+4*hi, col q = l31
    f32x16 sc2[2] = {};
#pragma unroll
    for (int c = 0; c < 4; c++) {
      const int dblk = (c * 16 + hi * 8) ^ swz;
#pragma unroll
      for (int kvh = 0; kvh < 2; kvh++) {
        bf16x8 kf = *(const bf16x8*)&Kc[(kvh * 32 + l31) * 64 + dblk];
        sc2[kvh] = MFMA32(kf, qf[c], sc2[kvh]);
      }
    }
    if (it == qt) {  // causal mask on diagonal tile
      const int q = qh * 32 + l31;
#pragma unroll
      for (int kvh = 0; kvh < 2; kvh++)
#pragma unroll
        for (int r = 0; r < 16; r++) {
          const int kv = kvh * 32 + (r & 3) + 8 * (r >> 2) + 4 * hi;
          if (kv > q) sc2[kvh][r] = -30000.0f;
        }
    }
    // row max: in-register over this lane's 32 rows + partner lane (other 32)
    float tm = fmaxf(sc2[0][0], sc2[0][1]);
#pragma unroll
    for (int kvh = 0; kvh < 2; kvh++)
#pragma unroll
      for (int r = (kvh ? 0 : 2); r < 16; r++) tm = fmaxf(tm, sc2[kvh][r]);
    tm = fmaxf(tm, __shfl_xor(tm, 32));
    // defer-max (T13): rescale only if max grew by > 8 (log2 units)
    if (__any(tm > mrow + 8.0f)) {
      const float mnew = fmaxf(mrow, tm);
      const float scl = __builtin_amdgcn_exp2f(mrow - mnew);
      mrow = mnew;
      srow *= scl;
#pragma unroll
      for (int dh = 0; dh < 2; dh++)
#pragma unroll
        for (int r = 0; r < 16; r++) ot[dh][r] *= scl;
    }
    // P = exp2(S - m), packed in-register; PV per kvh-half (only 8 pk words live at a time)
    float ps = 0.f;
#pragma unroll
    for (int kvh = 0; kvh < 2; kvh++) {
      unsigned pk[8];
#pragma unroll
      for (int j8 = 0; j8 < 8; j8++) {
        const float p0 = __builtin_amdgcn_exp2f(sc2[kvh][2 * j8] - mrow);
        const float p1 = __builtin_amdgcn_exp2f(sc2[kvh][2 * j8 + 1] - mrow);
        ps += p0 + p1;
        pk[j8] = pack2(p0, p1);     // kv pair base 8*(j8>>1)+2*(j8&1)+4*hi (+32*kvh)
      }
      // O^T += V^T P for chunks t = 2*kvh + tt
#pragma unroll
      for (int tt = 0; tt < 2; tt++) {
        const int t = kvh * 2 + tt;
        const unsigned a0 = pk[4 * tt + 0], a1 = pk[4 * tt + 1];
        const unsigned b0 = pk[4 * tt + 2], b1 = pk[4 * tt + 3];
        // send what the PARTNER needs; receive what WE need (partner's 4*tt + 2*hi + q)
        const unsigned s0 = hi ? a0 : b0, s1 = hi ? a1 : b1;
        const unsigned r0 = (unsigned)__shfl_xor((int)s0, 32);
        const unsigned r1 = (unsigned)__shfl_xor((int)s1, 32);
        u32x4 pw;
        pw[0] = hi ? r0 : a0;   // kv 16t+8hi+0,1
        pw[1] = hi ? r1 : a1;   // kv 16t+8hi+2,3
        pw[2] = hi ? b0 : r0;   // kv 16t+8hi+4,5
        pw[3] = hi ? b1 : r1;   // kv 16t+8hi+6,7
        const bf16x8 pf = __builtin_bit_cast(bf16x8, pw);
#pragma unroll
        for (int dh = 0; dh < 2; dh++) {
          bf16x8 vf = ld2x64(&Vc[(dh * 32 + l31) * 68 + t * 16 + hi * 8]);
          ot[dh] = MFMA32(vf, pf, ot[dh]);
        }
      }
    }
    ps += __shfl_xor(ps, 32);
    srow += ps;
    if (pre) {  // deferred V write into next buffer
#pragma unroll
      for (int s = 0; s < 2; s++) {
        const int cid = s * 256 + tid;
        const int row = cid >> 3, c8 = cid & 7;
#pragma unroll
        for (int j8 = 0; j8 < 8; j8++) {
          const int jj = (j8 + c8) & 7;
          const int d = c8 * 8 + jj;
          Vt[cur ^ 1][d * 68 + row] = vnx[s][jj];
        }
      }
    }
    cur ^= 1;
  }
  // epilogue: transpose O^T -> O through LDS (K buffers are dead), coalesced store
  __syncthreads();                     // all waves done reading K/V
  u16* Sx = &Ks[0][0] + wv * 2048;     // per-wave [32 q][64 d] swizzled scratch (4KB x 4 waves)
  const float inv = 1.0f / srow;
#pragma unroll
  for (int dh = 0; dh < 2; dh++)
#pragma unroll
    for (int jr = 0; jr < 8; jr++) {   // regs (2jr, 2jr+1) -> adjacent d
      const unsigned w = pack2(ot[dh][2 * jr] * inv, ot[dh][2 * jr + 1] * inv);
      const int d = dh * 32 + 8 * (jr >> 1) + (jr & 1) * 2 + 4 * hi;
      *(unsigned*)&Sx[l31 * 64 + (d ^ swz)] = w;
    }
  __syncthreads();   // make scratch writes visible before readback
#pragma unroll
  for (int rep = 0; rep < 4; rep++) {
    const int chunk = rep * 64 + lane;
    const int qr = chunk >> 3, cc = chunk & 7;
    u16x8 val = *(const u16x8*)&Sx[qr * 64 + ((cc * 8) ^ ((qr & 7) << 3))];
    *(u16x8*)&Ab[(size_t)(b * 2048 + q0 + qh * 32 + qr) * 2048 + h * 64 + cc * 8] = val;
  }
}

extern "C" void kernel_launch(void* const* d_in, const int* in_sizes, int n_in,
                              void* d_out, int out_size, void* d_ws, size_t ws_size,
                              hipStream_t stream) {
  const float* x  = (const float*)d_in[0];
  const float* Wq = (const float*)d_in[1];
  const float* bq = (const float*)d_in[2];
  const float* Wk = (const float*)d_in[3];
  const float* bk = (const float*)d_in[4];
  const float* Wv = (const float*)d_in[5];
  const float* bv = (const float*)d_in[6];
  const float* Wo = (const float*)d_in[7];
  const float* bo = (const float*)d_in[8];

  char* ws = (char*)d_ws;
  u16* xb  = (u16*)(ws + 0);          // 4096*2048 bf16 = 16 MiB
  u16* Ab  = (u16*)(ws + 0);          // aliases xb (xb dead after QKV gemm)
  u16* Qb  = (u16*)(ws + 16777216);   // 4096*2048
  u16* Kb  = (u16*)(ws + 33554432);   // 4096*512
  u16* Vb  = (u16*)(ws + 37748736);   // 4096*512
  u16* Wqt = (u16*)(ws + 41943040);   // 2048*2048
  u16* Wkt = (u16*)(ws + 50331648);   // 512*2048
  u16* Wvt = (u16*)(ws + 52428800);   // 512*2048
  u16* Wot = (u16*)(ws + 54525952);   // 2048*2048

  cvt_kernel<<<8192, 256, 0, stream>>>(x, xb, 2 * 2048 * 2048);
  cvt_t_all_kernel<<<dim3(160, 64), 256, 0, stream>>>(Wq, Wk, Wv, Wo, Wqt, Wkt, Wvt, Wot);

  qkv_gemm_kernel<<<dim3(24, 32), 512, 0, stream>>>(xb, Wqt, Wkt, Wvt, bq, bk, bv, Qb, Kb, Vb);
  attn_kernel<<<dim3(1024), 256, 0, stream>>>(Qb, Kb, Vb, Ab);
  oproj_kernel<<<dim3(16, 32), 512, 0, stream>>>(Ab, Wot, bo, (float*)d_out);
}

// Round 14
// 210.644 us; speedup vs baseline: 1.0441x; 1.0441x over previous
//
#include <hip/hip_runtime.h>
#include <hip/hip_bf16.h>

typedef unsigned short u16;
typedef __attribute__((ext_vector_type(8)))  __bf16 bf16x8;
typedef __attribute__((ext_vector_type(8)))  unsigned short u16x8;
typedef __attribute__((ext_vector_type(4)))  unsigned short u16x4;
typedef __attribute__((ext_vector_type(4)))  float f32x4;
typedef __attribute__((ext_vector_type(16))) float f32x16;
typedef __attribute__((ext_vector_type(4)))  unsigned u32x4;

#define MFMA(a, b, c)   __builtin_amdgcn_mfma_f32_16x16x32_bf16((a), (b), (c), 0, 0, 0)
#define MFMA32(a, b, c) __builtin_amdgcn_mfma_f32_32x32x16_bf16((a), (b), (c), 0, 0, 0)

// f32 -> bf16 round-to-nearest-even (bit trick)
__device__ __forceinline__ u16 f2b(float f) {
  union { float f; unsigned u; } x; x.f = f;
  unsigned r = x.u + 0x7fffu + ((x.u >> 16) & 1u);
  return (u16)(r >> 16);
}

__device__ __forceinline__ unsigned pack2(float lo, float hi) {
  const __bf16 a = (__bf16)lo, b = (__bf16)hi;
  return (unsigned)__builtin_bit_cast(u16, a) | ((unsigned)__builtin_bit_cast(u16, b) << 16);
}

// two 8B LDS loads -> one bf16x8 fragment (for 136B-stride rows: 2-way banks, 8B aligned)
__device__ __forceinline__ bf16x8 ld2x64(const u16* p) {
  union { u16x4 h[2]; bf16x8 v; } u;
  u.h[0] = *(const u16x4*)p;
  u.h[1] = *(const u16x4*)(p + 4);
  return u.v;
}

__device__ __forceinline__ void gl_lds16(void* lds, const void* g) {
  __builtin_amdgcn_global_load_lds(
      (const __attribute__((address_space(1))) void*)g,
      (__attribute__((address_space(3))) void*)lds, 16, 0, 0);
}

// ---------------- f32 -> bf16 elementwise ----------------
__global__ __launch_bounds__(256) void cvt_kernel(const float* __restrict__ in,
                                                  u16* __restrict__ out, int n) {
  int i = (blockIdx.x * 256 + threadIdx.x) * 4;
  if (i >= n) return;
  f32x4 v = *(const f32x4*)(in + i);
  u16x4 o;
  o[0] = f2b(v[0]); o[1] = f2b(v[1]); o[2] = f2b(v[2]); o[3] = f2b(v[3]);
  *(u16x4*)(out + i) = o;
}

// ---------------- fused f32 [K=2048][N] -> bf16 [N][K] transposes for all 4 weights ----------
// grid (160, 64): x<64 -> Wq, x<80 -> Wk, x<96 -> Wv, else Wo. One launch instead of four.
__global__ __launch_bounds__(256) void cvt_t_all_kernel(
    const float* __restrict__ Wq, const float* __restrict__ Wk,
    const float* __restrict__ Wv, const float* __restrict__ Wo,
    u16* __restrict__ Wqt, u16* __restrict__ Wkt,
    u16* __restrict__ Wvt, u16* __restrict__ Wot) {
  __shared__ u16 t[32][36];
  const int x = blockIdx.x;
  const float* W; u16* Wt; int N, n0;
  if (x < 64)      { W = Wq; Wt = Wqt; N = 2048; n0 = x * 32; }
  else if (x < 80) { W = Wk; Wt = Wkt; N = 512;  n0 = (x - 64) * 32; }
  else if (x < 96) { W = Wv; Wt = Wvt; N = 512;  n0 = (x - 80) * 32; }
  else             { W = Wo; Wt = Wot; N = 2048; n0 = (x - 96) * 32; }
  const int k0 = blockIdx.y * 32;
  const int r = threadIdx.x >> 3, c4 = (threadIdx.x & 7) * 4;
  f32x4 v = *(const f32x4*)&W[(size_t)(k0 + r) * N + n0 + c4];
  t[c4 + 0][r] = f2b(v[0]);
  t[c4 + 1][r] = f2b(v[1]);
  t[c4 + 2][r] = f2b(v[2]);
  t[c4 + 3][r] = f2b(v[3]);
  __syncthreads();
  u16x4 o;
  o[0] = t[r][c4]; o[1] = t[r][c4 + 1]; o[2] = t[r][c4 + 2]; o[3] = t[r][c4 + 3];
  *(u16x4*)&Wt[(size_t)(n0 + r) * 2048 + k0 + c4] = o;
}

// ---------------- shared GEMM body: C[M=4096][N] = A[4096][2048] @ Bt[N][2048]^T + bias ----------------
// 8-wave / 512-thread variant of the R7-proven 1-phase structure (R12-verified).
template <bool OUT_BF16>
__device__ __forceinline__ void gemm_body(const u16* __restrict__ A, const u16* __restrict__ Bt,
                                          const float* __restrict__ bias, void* __restrict__ C,
                                          const int N, const int n0, const int m0, const float scale) {
  __shared__ __align__(16) u16 As[128 * 32];
  __shared__ __align__(16) u16 Bs[128 * 32];
  const int tid = threadIdx.x;
  const int lane = tid & 63, wv = tid >> 6;
  const int l15 = lane & 15, lg = lane >> 4;
  const int wm = wv >> 2, wn = wv & 3;     // 2 x 4 wave grid
  const int srow = tid >> 2;               // staging row 0..127
  const int g = tid & 3;
  const int gs = g ^ ((srow >> 1) & 3);    // inverse-swizzled source chunk (rule #21)

  f32x4 acc[4][2] = {};

  for (int k0 = 0; k0 < 2048; k0 += 32) {
    gl_lds16(&As[wv << 9], A  + (((size_t)(m0 + srow)) << 11) + k0 + gs * 8);
    gl_lds16(&Bs[wv << 9], Bt + (((size_t)(n0 + srow)) << 11) + k0 + gs * 8);
    __syncthreads();
    bf16x8 af[4], bfr[2];
#pragma unroll
    for (int t = 0; t < 4; t++) {
      const int ra = wm * 64 + t * 16 + l15;
      af[t] = *(const bf16x8*)&As[ra * 32 + ((lg ^ ((ra >> 1) & 3)) << 3)];
    }
#pragma unroll
    for (int u = 0; u < 2; u++) {
      const int rb = wn * 32 + u * 16 + l15;
      bfr[u] = *(const bf16x8*)&Bs[rb * 32 + ((lg ^ ((rb >> 1) & 3)) << 3)];
    }
#pragma unroll
    for (int mt = 0; mt < 4; mt++)
#pragma unroll
      for (int nt = 0; nt < 2; nt++)
        acc[mt][nt] = MFMA(af[mt], bfr[nt], acc[mt][nt]);
    __syncthreads();
  }

#pragma unroll
  for (int nt = 0; nt < 2; nt++) {
    const int col = n0 + wn * 32 + nt * 16 + l15;
    const float bc = bias[col];
#pragma unroll
    for (int mt = 0; mt < 4; mt++) {
#pragma unroll
      for (int r = 0; r < 4; r++) {
        const int row = m0 + wm * 64 + mt * 16 + lg * 4 + r;
        const float v = (acc[mt][nt][r] + bc) * scale;
        if (OUT_BF16) ((u16*)C)[(size_t)row * N + col] = f2b(v);
        else          ((float*)C)[(size_t)row * N + col] = v;
      }
    }
  }
}

// Fused QKV projection. Q is pre-scaled by (1/sqrt(64)) * log2(e) so attention uses exp2.
__global__ __launch_bounds__(512, 6) void qkv_gemm_kernel(
    const u16* __restrict__ xb,
    const u16* __restrict__ Wqt, const u16* __restrict__ Wkt, const u16* __restrict__ Wvt,
    const float* __restrict__ bq, const float* __restrict__ bk, const float* __restrict__ bv,
    u16* __restrict__ Qb, u16* __restrict__ Kb, u16* __restrict__ Vb) {
  const int nb = blockIdx.x;
  const u16* Bt; const float* bias; u16* out; int N, n0; float scale;
  if (nb < 16)      { Bt = Wqt; bias = bq; out = Qb; N = 2048; n0 = nb * 128;        scale = 0.125f * 1.44269504f; }
  else if (nb < 20) { Bt = Wkt; bias = bk; out = Kb; N = 512;  n0 = (nb - 16) * 128; scale = 1.0f; }
  else              { Bt = Wvt; bias = bv; out = Vb; N = 512;  n0 = (nb - 20) * 128; scale = 1.0f; }
  gemm_body<true>(xb, Bt, bias, out, N, n0, blockIdx.y * 128, scale);
}

__global__ __launch_bounds__(512, 6) void oproj_kernel(const u16* __restrict__ Ab,
                                                       const u16* __restrict__ Wot,
                                                       const float* __restrict__ bo,
                                                       float* __restrict__ out) {
  gemm_body<false>(Ab, Wot, bo, out, 2048, blockIdx.x * 128, blockIdx.y * 128, 1.0f);
}

// ---------------- causal GQA flash attention (32x32 swapped-operand, fully in-register P) ----
// EXACT R12 configuration (best measured: 87 us). grid = 512 blocks x 512 threads (8 waves =
// 4 heads x 2 q-halves of 32); KV staged once per 4 heads. Block i (i<256): qt=31-(i>>4);
// block i+256: qt=(i>>4) (complementary pair shares (kh,b) and lands on the same XCD since
// 256%8==0). P exchanged via __shfl_xor(,32)+selects; V^T stride-68 LDS; K gl_lds+XOR swizzle.
__global__ __launch_bounds__(512, 4) void attn_kernel(const u16* __restrict__ Qb,
                                                      const u16* __restrict__ Kb,
                                                      const u16* __restrict__ Vb,
                                                      u16* __restrict__ Ab) {
  const int i = blockIdx.x;
  const int j = i & 255;
  const int kh = j & 7, b = (j >> 3) & 1;
  const int p16 = j >> 4;                       // 0..15
  const int qt = (i < 256) ? (31 - p16) : p16;  // complementary-length pairing

  const int tid = threadIdx.x;
  const int lane = tid & 63, wv = tid >> 6;
  const int hh = wv & 3, qh = wv >> 2;      // head-in-group, q-half
  const int h = kh * 4 + hh;
  const int l31 = lane & 31, hi = lane >> 5;
  const int swz = (l31 & 7) << 3;

  __shared__ __align__(16) u16 Ks[2][64 * 64];   // K[kv][d ^ ((kv&7)<<3)] (gl_lds, rule #21)
  __shared__ __align__(16) u16 Vt[2][64 * 68];   // V^T[d][kv], stride 68 (2-way banks)

  const int skv = tid >> 3;      // kv row staged by this thread (0..63)
  const int sc8 = tid & 7;       // 16B chunk / d0-block
  const int sd0 = sc8 * 8;

  const u16* Kbase = Kb + (size_t)(b * 2048) * 512 + kh * 64;
  const u16* Vbase = Vb + (size_t)(b * 2048) * 512 + kh * 64;

  const int q0 = qt * 64;

  // Q B-frags: col = q = l31, k = d = c*16 + hi*8 + j
  bf16x8 qf[4];
  {
    const u16* qp = Qb + (size_t)(b * 2048 + q0 + qh * 32 + l31) * 2048 + h * 64 + hi * 8;
#pragma unroll
    for (int c = 0; c < 4; c++) qf[c] = *(const bf16x8*)(qp + c * 16);
  }
  f32x16 ot[2] = {};              // O^T acc: row d = dh*32 + (reg&3)+8*(reg>>2)+4*hi, col q
  float mrow = -30000.0f, srow = 0.f;

  int cur = 0;
  {  // prologue: stage tile 0 into buf 0
    gl_lds16(&Ks[0][wv << 9], Kbase + ((size_t)skv << 9) + ((sc8 ^ (skv & 7)) << 3));
    u16x8 vr = *(const u16x8*)(Vbase + ((size_t)skv << 9) + sd0);
#pragma unroll
    for (int j8 = 0; j8 < 8; j8++) {
      const int jj = (j8 + sc8) & 7;      // rotate so concurrent lanes spread banks
      const int d = sd0 + jj;
      Vt[0][d * 68 + skv] = vr[jj];
    }
  }
  for (int it = 0; it <= qt; ++it) {
    __syncthreads();   // buf[cur] fully staged (drains each wave's vmcnt+lgkm, then barrier)
    const bool pre = (it < qt);
    u16x8 vnx;
    if (pre) {  // issue next tile's loads early; V LDS-write deferred past compute
      const size_t roff = (size_t)((it + 1) * 64 + skv) << 9;
      gl_lds16(&Ks[cur ^ 1][wv << 9], Kbase + roff + ((sc8 ^ (skv & 7)) << 3));
      vnx = *(const u16x8*)(Vbase + roff + sd0);
    }
    const u16* Kc = Ks[cur];
    const u16* Vc = Vt[cur];

    // S = K Q : sc2[kvh] rows kv = kvh*32 + (reg&3)+8*(reg>>2)+4*hi, col q = l31
    f32x16 sc2[2] = {};
#pragma unroll
    for (int c = 0; c < 4; c++) {
      const int dblk = (c * 16 + hi * 8) ^ swz;
#pragma unroll
      for (int kvh = 0; kvh < 2; kvh++) {
        bf16x8 kf = *(const bf16x8*)&Kc[(kvh * 32 + l31) * 64 + dblk];
        sc2[kvh] = MFMA32(kf, qf[c], sc2[kvh]);
      }
    }
    if (it == qt) {  // causal mask on diagonal tile
      const int q = qh * 32 + l31;
#pragma unroll
      for (int kvh = 0; kvh < 2; kvh++)
#pragma unroll
        for (int r = 0; r < 16; r++) {
          const int kv = kvh * 32 + (r & 3) + 8 * (r >> 2) + 4 * hi;
          if (kv > q) sc2[kvh][r] = -30000.0f;
        }
    }
    // row max: in-register over this lane's 32 rows + partner lane (other 32)
    float tm = fmaxf(sc2[0][0], sc2[0][1]);
#pragma unroll
    for (int kvh = 0; kvh < 2; kvh++)
#pragma unroll
      for (int r = (kvh ? 0 : 2); r < 16; r++) tm = fmaxf(tm, sc2[kvh][r]);
    tm = fmaxf(tm, __shfl_xor(tm, 32));
    // defer-max (T13): rescale only if max grew by > 8 (log2 units)
    if (__any(tm > mrow + 8.0f)) {
      const float mnew = fmaxf(mrow, tm);
      const float scl = __builtin_amdgcn_exp2f(mrow - mnew);
      mrow = mnew;
      srow *= scl;
#pragma unroll
      for (int dh = 0; dh < 2; dh++)
#pragma unroll
        for (int r = 0; r < 16; r++) ot[dh][r] *= scl;
    }
    // P = exp2(S - m), packed in-register; PV per kvh-half (only 8 pk words live at a time)
    float ps = 0.f;
#pragma unroll
    for (int kvh = 0; kvh < 2; kvh++) {
      unsigned pk[8];
#pragma unroll
      for (int j8 = 0; j8 < 8; j8++) {
        const float p0 = __builtin_amdgcn_exp2f(sc2[kvh][2 * j8] - mrow);
        const float p1 = __builtin_amdgcn_exp2f(sc2[kvh][2 * j8 + 1] - mrow);
        ps += p0 + p1;
        pk[j8] = pack2(p0, p1);     // kv pair base 8*(j8>>1)+2*(j8&1)+4*hi (+32*kvh)
      }
      // O^T += V^T P for chunks t = 2*kvh + tt
#pragma unroll
      for (int tt = 0; tt < 2; tt++) {
        const int t = kvh * 2 + tt;
        const unsigned a0 = pk[4 * tt + 0], a1 = pk[4 * tt + 1];
        const unsigned b0 = pk[4 * tt + 2], b1 = pk[4 * tt + 3];
        // send what the PARTNER needs; receive what WE need (partner's 4*tt + 2*hi + q)
        const unsigned s0 = hi ? a0 : b0, s1 = hi ? a1 : b1;
        const unsigned r0 = (unsigned)__shfl_xor((int)s0, 32);
        const unsigned r1 = (unsigned)__shfl_xor((int)s1, 32);
        u32x4 pw;
        pw[0] = hi ? r0 : a0;   // kv 16t+8hi+0,1
        pw[1] = hi ? r1 : a1;   // kv 16t+8hi+2,3
        pw[2] = hi ? b0 : r0;   // kv 16t+8hi+4,5
        pw[3] = hi ? b1 : r1;   // kv 16t+8hi+6,7
        const bf16x8 pf = __builtin_bit_cast(bf16x8, pw);
#pragma unroll
        for (int dh = 0; dh < 2; dh++) {
          bf16x8 vf = ld2x64(&Vc[(dh * 32 + l31) * 68 + t * 16 + hi * 8]);
          ot[dh] = MFMA32(vf, pf, ot[dh]);
        }
      }
    }
    ps += __shfl_xor(ps, 32);
    srow += ps;
    if (pre) {  // deferred V write into next buffer
#pragma unroll
      for (int j8 = 0; j8 < 8; j8++) {
        const int jj = (j8 + sc8) & 7;
        const int d = sd0 + jj;
        Vt[cur ^ 1][d * 68 + skv] = vnx[jj];
      }
    }
    cur ^= 1;
  }
  // epilogue: transpose O^T -> O through LDS (K/V buffers are dead), coalesced store
  __syncthreads();                     // all waves done reading K/V
  u16* Sx = (wv < 4) ? &Ks[0][0] + wv * 2048 : &Vt[0][0] + (wv - 4) * 2048;  // 4KB/wave scratch
  const float inv = 1.0f / srow;
#pragma unroll
  for (int dh = 0; dh < 2; dh++)
#pragma unroll
    for (int jr = 0; jr < 8; jr++) {   // regs (2jr, 2jr+1) -> adjacent d
      const unsigned w = pack2(ot[dh][2 * jr] * inv, ot[dh][2 * jr + 1] * inv);
      const int d = dh * 32 + 8 * (jr >> 1) + (jr & 1) * 2 + 4 * hi;
      *(unsigned*)&Sx[l31 * 64 + (d ^ swz)] = w;
    }
  __syncthreads();   // make scratch writes visible before readback
#pragma unroll
  for (int rep = 0; rep < 4; rep++) {
    const int chunk = rep * 64 + lane;
    const int qr = chunk >> 3, cc = chunk & 7;
    u16x8 val = *(const u16x8*)&Sx[qr * 64 + ((cc * 8) ^ ((qr & 7) << 3))];
    *(u16x8*)&Ab[(size_t)(b * 2048 + q0 + qh * 32 + qr) * 2048 + h * 64 + cc * 8] = val;
  }
}

extern "C" void kernel_launch(void* const* d_in, const int* in_sizes, int n_in,
                              void* d_out, int out_size, void* d_ws, size_t ws_size,
                              hipStream_t stream) {
  const float* x  = (const float*)d_in[0];
  const float* Wq = (const float*)d_in[1];
  const float* bq = (const float*)d_in[2];
  const float* Wk = (const float*)d_in[3];
  const float* bk = (const float*)d_in[4];
  const float* Wv = (const float*)d_in[5];
  const float* bv = (const float*)d_in[6];
  const float* Wo = (const float*)d_in[7];
  const float* bo = (const float*)d_in[8];

  char* ws = (char*)d_ws;
  u16* xb  = (u16*)(ws + 0);          // 4096*2048 bf16 = 16 MiB
  u16* Ab  = (u16*)(ws + 0);          // aliases xb (xb dead after QKV gemm)
  u16* Qb  = (u16*)(ws + 16777216);   // 4096*2048
  u16* Kb  = (u16*)(ws + 33554432);   // 4096*512
  u16* Vb  = (u16*)(ws + 37748736);   // 4096*512
  u16* Wqt = (u16*)(ws + 41943040);   // 2048*2048
  u16* Wkt = (u16*)(ws + 50331648);   // 512*2048
  u16* Wvt = (u16*)(ws + 52428800);   // 512*2048
  u16* Wot = (u16*)(ws + 54525952);   // 2048*2048

  cvt_kernel<<<8192, 256, 0, stream>>>(x, xb, 2 * 2048 * 2048);
  cvt_t_all_kernel<<<dim3(160, 64), 256, 0, stream>>>(Wq, Wk, Wv, Wo, Wqt, Wkt, Wvt, Wot);

  qkv_gemm_kernel<<<dim3(24, 32), 512, 0, stream>>>(xb, Wqt, Wkt, Wvt, bq, bk, bv, Qb, Kb, Vb);
  attn_kernel<<<dim3(512), 512, 0, stream>>>(Qb, Kb, Vb, Ab);
  oproj_kernel<<<dim3(16, 32), 512, 0, stream>>>(Ab, Wot, bo, (float*)d_out);
}

// Round 15
// 209.460 us; speedup vs baseline: 1.0500x; 1.0057x over previous
//
#include <hip/hip_runtime.h>
#include <hip/hip_bf16.h>

typedef unsigned short u16;
typedef __attribute__((ext_vector_type(8)))  __bf16 bf16x8;
typedef __attribute__((ext_vector_type(8)))  unsigned short u16x8;
typedef __attribute__((ext_vector_type(4)))  unsigned short u16x4;
typedef __attribute__((ext_vector_type(4)))  float f32x4;
typedef __attribute__((ext_vector_type(16))) float f32x16;
typedef __attribute__((ext_vector_type(4)))  unsigned u32x4;

#define MFMA(a, b, c)   __builtin_amdgcn_mfma_f32_16x16x32_bf16((a), (b), (c), 0, 0, 0)
#define MFMA32(a, b, c) __builtin_amdgcn_mfma_f32_32x32x16_bf16((a), (b), (c), 0, 0, 0)

// f32 -> bf16 round-to-nearest-even (bit trick)
__device__ __forceinline__ u16 f2b(float f) {
  union { float f; unsigned u; } x; x.f = f;
  unsigned r = x.u + 0x7fffu + ((x.u >> 16) & 1u);
  return (u16)(r >> 16);
}

__device__ __forceinline__ unsigned pack2(float lo, float hi) {
  const __bf16 a = (__bf16)lo, b = (__bf16)hi;
  return (unsigned)__builtin_bit_cast(u16, a) | ((unsigned)__builtin_bit_cast(u16, b) << 16);
}

// two 8B LDS loads -> one bf16x8 fragment (for 136B-stride rows: 2-way banks, 8B aligned)
__device__ __forceinline__ bf16x8 ld2x64(const u16* p) {
  union { u16x4 h[2]; bf16x8 v; } u;
  u.h[0] = *(const u16x4*)p;
  u.h[1] = *(const u16x4*)(p + 4);
  return u.v;
}

__device__ __forceinline__ void gl_lds16(void* lds, const void* g) {
  __builtin_amdgcn_global_load_lds(
      (const __attribute__((address_space(1))) void*)g,
      (__attribute__((address_space(3))) void*)lds, 16, 0, 0);
}

// ---------------- f32 -> bf16 elementwise ----------------
__global__ __launch_bounds__(256) void cvt_kernel(const float* __restrict__ in,
                                                  u16* __restrict__ out, int n) {
  int i = (blockIdx.x * 256 + threadIdx.x) * 4;
  if (i >= n) return;
  f32x4 v = *(const f32x4*)(in + i);
  u16x4 o;
  o[0] = f2b(v[0]); o[1] = f2b(v[1]); o[2] = f2b(v[2]); o[3] = f2b(v[3]);
  *(u16x4*)(out + i) = o;
}

// ---------------- fused f32 [K=2048][N] -> bf16 [N][K] transposes for all 4 weights ----------
// grid (160, 64): x<64 -> Wq, x<80 -> Wk, x<96 -> Wv, else Wo. One launch instead of four.
__global__ __launch_bounds__(256) void cvt_t_all_kernel(
    const float* __restrict__ Wq, const float* __restrict__ Wk,
    const float* __restrict__ Wv, const float* __restrict__ Wo,
    u16* __restrict__ Wqt, u16* __restrict__ Wkt,
    u16* __restrict__ Wvt, u16* __restrict__ Wot) {
  __shared__ u16 t[32][36];
  const int x = blockIdx.x;
  const float* W; u16* Wt; int N, n0;
  if (x < 64)      { W = Wq; Wt = Wqt; N = 2048; n0 = x * 32; }
  else if (x < 80) { W = Wk; Wt = Wkt; N = 512;  n0 = (x - 64) * 32; }
  else if (x < 96) { W = Wv; Wt = Wvt; N = 512;  n0 = (x - 80) * 32; }
  else             { W = Wo; Wt = Wot; N = 2048; n0 = (x - 96) * 32; }
  const int k0 = blockIdx.y * 32;
  const int r = threadIdx.x >> 3, c4 = (threadIdx.x & 7) * 4;
  f32x4 v = *(const f32x4*)&W[(size_t)(k0 + r) * N + n0 + c4];
  t[c4 + 0][r] = f2b(v[0]);
  t[c4 + 1][r] = f2b(v[1]);
  t[c4 + 2][r] = f2b(v[2]);
  t[c4 + 3][r] = f2b(v[3]);
  __syncthreads();
  u16x4 o;
  o[0] = t[r][c4]; o[1] = t[r][c4 + 1]; o[2] = t[r][c4 + 2]; o[3] = t[r][c4 + 3];
  *(u16x4*)&Wt[(size_t)(n0 + r) * 2048 + k0 + c4] = o;
}

// ---------------- shared GEMM body: C[M=4096][N] = A[4096][2048] @ Bt[N][2048]^T + bias ----------------
// 8-wave / 512-thread variant of the R7-proven 1-phase structure (R12-verified).
template <bool OUT_BF16>
__device__ __forceinline__ void gemm_body(const u16* __restrict__ A, const u16* __restrict__ Bt,
                                          const float* __restrict__ bias, void* __restrict__ C,
                                          const int N, const int n0, const int m0, const float scale) {
  __shared__ __align__(16) u16 As[128 * 32];
  __shared__ __align__(16) u16 Bs[128 * 32];
  const int tid = threadIdx.x;
  const int lane = tid & 63, wv = tid >> 6;
  const int l15 = lane & 15, lg = lane >> 4;
  const int wm = wv >> 2, wn = wv & 3;     // 2 x 4 wave grid
  const int srow = tid >> 2;               // staging row 0..127
  const int g = tid & 3;
  const int gs = g ^ ((srow >> 1) & 3);    // inverse-swizzled source chunk (rule #21)

  f32x4 acc[4][2] = {};

  for (int k0 = 0; k0 < 2048; k0 += 32) {
    gl_lds16(&As[wv << 9], A  + (((size_t)(m0 + srow)) << 11) + k0 + gs * 8);
    gl_lds16(&Bs[wv << 9], Bt + (((size_t)(n0 + srow)) << 11) + k0 + gs * 8);
    __syncthreads();
    bf16x8 af[4], bfr[2];
#pragma unroll
    for (int t = 0; t < 4; t++) {
      const int ra = wm * 64 + t * 16 + l15;
      af[t] = *(const bf16x8*)&As[ra * 32 + ((lg ^ ((ra >> 1) & 3)) << 3)];
    }
#pragma unroll
    for (int u = 0; u < 2; u++) {
      const int rb = wn * 32 + u * 16 + l15;
      bfr[u] = *(const bf16x8*)&Bs[rb * 32 + ((lg ^ ((rb >> 1) & 3)) << 3)];
    }
#pragma unroll
    for (int mt = 0; mt < 4; mt++)
#pragma unroll
      for (int nt = 0; nt < 2; nt++)
        acc[mt][nt] = MFMA(af[mt], bfr[nt], acc[mt][nt]);
    __syncthreads();
  }

#pragma unroll
  for (int nt = 0; nt < 2; nt++) {
    const int col = n0 + wn * 32 + nt * 16 + l15;
    const float bc = bias[col];
#pragma unroll
    for (int mt = 0; mt < 4; mt++) {
#pragma unroll
      for (int r = 0; r < 4; r++) {
        const int row = m0 + wm * 64 + mt * 16 + lg * 4 + r;
        const float v = (acc[mt][nt][r] + bc) * scale;
        if (OUT_BF16) ((u16*)C)[(size_t)row * N + col] = f2b(v);
        else          ((float*)C)[(size_t)row * N + col] = v;
      }
    }
  }
}

// Fused QKV projection. Q is pre-scaled by (1/sqrt(64)) * log2(e) so attention uses exp2.
__global__ __launch_bounds__(512, 6) void qkv_gemm_kernel(
    const u16* __restrict__ xb,
    const u16* __restrict__ Wqt, const u16* __restrict__ Wkt, const u16* __restrict__ Wvt,
    const float* __restrict__ bq, const float* __restrict__ bk, const float* __restrict__ bv,
    u16* __restrict__ Qb, u16* __restrict__ Kb, u16* __restrict__ Vb) {
  const int nb = blockIdx.x;
  const u16* Bt; const float* bias; u16* out; int N, n0; float scale;
  if (nb < 16)      { Bt = Wqt; bias = bq; out = Qb; N = 2048; n0 = nb * 128;        scale = 0.125f * 1.44269504f; }
  else if (nb < 20) { Bt = Wkt; bias = bk; out = Kb; N = 512;  n0 = (nb - 16) * 128; scale = 1.0f; }
  else              { Bt = Wvt; bias = bv; out = Vb; N = 512;  n0 = (nb - 20) * 128; scale = 1.0f; }
  gemm_body<true>(xb, Bt, bias, out, N, n0, blockIdx.y * 128, scale);
}

__global__ __launch_bounds__(512, 6) void oproj_kernel(const u16* __restrict__ Ab,
                                                       const u16* __restrict__ Wot,
                                                       const float* __restrict__ bo,
                                                       float* __restrict__ out) {
  gemm_body<false>(Ab, Wot, bo, out, 2048, blockIdx.x * 128, blockIdx.y * 128, 1.0f);
}

// ---------------- causal GQA flash attention (32x32 swapped-operand, fully in-register P) ----
// EXACT R12 configuration (best measured: 87 us). grid = 512 blocks x 512 threads (8 waves =
// 4 heads x 2 q-halves of 32); KV staged once per 4 heads. Block i (i<256): qt=31-(i>>4);
// block i+256: qt=(i>>4) (complementary pair shares (kh,b) and lands on the same XCD since
// 256%8==0). P exchanged via __shfl_xor(,32)+selects; V^T stride-68 LDS; K gl_lds+XOR swizzle.
__global__ __launch_bounds__(512, 4) void attn_kernel(const u16* __restrict__ Qb,
                                                      const u16* __restrict__ Kb,
                                                      const u16* __restrict__ Vb,
                                                      u16* __restrict__ Ab) {
  const int i = blockIdx.x;
  const int j = i & 255;
  const int kh = j & 7, b = (j >> 3) & 1;
  const int p16 = j >> 4;                       // 0..15
  const int qt = (i < 256) ? (31 - p16) : p16;  // complementary-length pairing

  const int tid = threadIdx.x;
  const int lane = tid & 63, wv = tid >> 6;
  const int hh = wv & 3, qh = wv >> 2;      // head-in-group, q-half
  const int h = kh * 4 + hh;
  const int l31 = lane & 31, hi = lane >> 5;
  const int swz = (l31 & 7) << 3;

  __shared__ __align__(16) u16 Ks[2][64 * 64];   // K[kv][d ^ ((kv&7)<<3)] (gl_lds, rule #21)
  __shared__ __align__(16) u16 Vt[2][64 * 68];   // V^T[d][kv], stride 68 (2-way banks)

  const int skv = tid >> 3;      // kv row staged by this thread (0..63)
  const int sc8 = tid & 7;       // 16B chunk / d0-block
  const int sd0 = sc8 * 8;

  const u16* Kbase = Kb + (size_t)(b * 2048) * 512 + kh * 64;
  const u16* Vbase = Vb + (size_t)(b * 2048) * 512 + kh * 64;

  const int q0 = qt * 64;

  // Q B-frags: col = q = l31, k = d = c*16 + hi*8 + j
  bf16x8 qf[4];
  {
    const u16* qp = Qb + (size_t)(b * 2048 + q0 + qh * 32 + l31) * 2048 + h * 64 + hi * 8;
#pragma unroll
    for (int c = 0; c < 4; c++) qf[c] = *(const bf16x8*)(qp + c * 16);
  }
  f32x16 ot[2] = {};              // O^T acc: row d = dh*32 + (reg&3)+8*(reg>>2)+4*hi, col q
  float mrow = -30000.0f, srow = 0.f;

  int cur = 0;
  {  // prologue: stage tile 0 into buf 0
    gl_lds16(&Ks[0][wv << 9], Kbase + ((size_t)skv << 9) + ((sc8 ^ (skv & 7)) << 3));
    u16x8 vr = *(const u16x8*)(Vbase + ((size_t)skv << 9) + sd0);
#pragma unroll
    for (int j8 = 0; j8 < 8; j8++) {
      const int jj = (j8 + sc8) & 7;      // rotate so concurrent lanes spread banks
      const int d = sd0 + jj;
      Vt[0][d * 68 + skv] = vr[jj];
    }
  }
  for (int it = 0; it <= qt; ++it) {
    __syncthreads();   // buf[cur] fully staged (drains each wave's vmcnt+lgkm, then barrier)
    const bool pre = (it < qt);
    u16x8 vnx;
    if (pre) {  // issue next tile's loads early; V LDS-write deferred past compute
      const size_t roff = (size_t)((it + 1) * 64 + skv) << 9;
      gl_lds16(&Ks[cur ^ 1][wv << 9], Kbase + roff + ((sc8 ^ (skv & 7)) << 3));
      vnx = *(const u16x8*)(Vbase + roff + sd0);
    }
    const u16* Kc = Ks[cur];
    const u16* Vc = Vt[cur];

    // S = K Q : sc2[kvh] rows kv = kvh*32 + (reg&3)+8*(reg>>2)+4*hi, col q = l31
    f32x16 sc2[2] = {};
#pragma unroll
    for (int c = 0; c < 4; c++) {
      const int dblk = (c * 16 + hi * 8) ^ swz;
#pragma unroll
      for (int kvh = 0; kvh < 2; kvh++) {
        bf16x8 kf = *(const bf16x8*)&Kc[(kvh * 32 + l31) * 64 + dblk];
        sc2[kvh] = MFMA32(kf, qf[c], sc2[kvh]);
      }
    }
    if (it == qt) {  // causal mask on diagonal tile
      const int q = qh * 32 + l31;
#pragma unroll
      for (int kvh = 0; kvh < 2; kvh++)
#pragma unroll
        for (int r = 0; r < 16; r++) {
          const int kv = kvh * 32 + (r & 3) + 8 * (r >> 2) + 4 * hi;
          if (kv > q) sc2[kvh][r] = -30000.0f;
        }
    }
    // row max: in-register over this lane's 32 rows + partner lane (other 32)
    float tm = fmaxf(sc2[0][0], sc2[0][1]);
#pragma unroll
    for (int kvh = 0; kvh < 2; kvh++)
#pragma unroll
      for (int r = (kvh ? 0 : 2); r < 16; r++) tm = fmaxf(tm, sc2[kvh][r]);
    tm = fmaxf(tm, __shfl_xor(tm, 32));
    // defer-max (T13): rescale only if max grew by > 8 (log2 units)
    if (__any(tm > mrow + 8.0f)) {
      const float mnew = fmaxf(mrow, tm);
      const float scl = __builtin_amdgcn_exp2f(mrow - mnew);
      mrow = mnew;
      srow *= scl;
#pragma unroll
      for (int dh = 0; dh < 2; dh++)
#pragma unroll
        for (int r = 0; r < 16; r++) ot[dh][r] *= scl;
    }
    // P = exp2(S - m), packed in-register; PV per kvh-half (only 8 pk words live at a time)
    float ps = 0.f;
#pragma unroll
    for (int kvh = 0; kvh < 2; kvh++) {
      unsigned pk[8];
#pragma unroll
      for (int j8 = 0; j8 < 8; j8++) {
        const float p0 = __builtin_amdgcn_exp2f(sc2[kvh][2 * j8] - mrow);
        const float p1 = __builtin_amdgcn_exp2f(sc2[kvh][2 * j8 + 1] - mrow);
        ps += p0 + p1;
        pk[j8] = pack2(p0, p1);     // kv pair base 8*(j8>>1)+2*(j8&1)+4*hi (+32*kvh)
      }
      // O^T += V^T P for chunks t = 2*kvh + tt
#pragma unroll
      for (int tt = 0; tt < 2; tt++) {
        const int t = kvh * 2 + tt;
        const unsigned a0 = pk[4 * tt + 0], a1 = pk[4 * tt + 1];
        const unsigned b0 = pk[4 * tt + 2], b1 = pk[4 * tt + 3];
        // send what the PARTNER needs; receive what WE need (partner's 4*tt + 2*hi + q)
        const unsigned s0 = hi ? a0 : b0, s1 = hi ? a1 : b1;
        const unsigned r0 = (unsigned)__shfl_xor((int)s0, 32);
        const unsigned r1 = (unsigned)__shfl_xor((int)s1, 32);
        u32x4 pw;
        pw[0] = hi ? r0 : a0;   // kv 16t+8hi+0,1
        pw[1] = hi ? r1 : a1;   // kv 16t+8hi+2,3
        pw[2] = hi ? b0 : r0;   // kv 16t+8hi+4,5
        pw[3] = hi ? b1 : r1;   // kv 16t+8hi+6,7
        const bf16x8 pf = __builtin_bit_cast(bf16x8, pw);
#pragma unroll
        for (int dh = 0; dh < 2; dh++) {
          bf16x8 vf = ld2x64(&Vc[(dh * 32 + l31) * 68 + t * 16 + hi * 8]);
          ot[dh] = MFMA32(vf, pf, ot[dh]);
        }
      }
    }
    ps += __shfl_xor(ps, 32);
    srow += ps;
    if (pre) {  // deferred V write into next buffer
#pragma unroll
      for (int j8 = 0; j8 < 8; j8++) {
        const int jj = (j8 + sc8) & 7;
        const int d = sd0 + jj;
        Vt[cur ^ 1][d * 68 + skv] = vnx[jj];
      }
    }
    cur ^= 1;
  }
  // epilogue: transpose O^T -> O through LDS (K/V buffers are dead), coalesced store
  __syncthreads();                     // all waves done reading K/V
  u16* Sx = (wv < 4) ? &Ks[0][0] + wv * 2048 : &Vt[0][0] + (wv - 4) * 2048;  // 4KB/wave scratch
  const float inv = 1.0f / srow;
#pragma unroll
  for (int dh = 0; dh < 2; dh++)
#pragma unroll
    for (int jr = 0; jr < 8; jr++) {   // regs (2jr, 2jr+1) -> adjacent d
      const unsigned w = pack2(ot[dh][2 * jr] * inv, ot[dh][2 * jr + 1] * inv);
      const int d = dh * 32 + 8 * (jr >> 1) + (jr & 1) * 2 + 4 * hi;
      *(unsigned*)&Sx[l31 * 64 + (d ^ swz)] = w;
    }
  __syncthreads();   // make scratch writes visible before readback
#pragma unroll
  for (int rep = 0; rep < 4; rep++) {
    const int chunk = rep * 64 + lane;
    const int qr = chunk >> 3, cc = chunk & 7;
    u16x8 val = *(const u16x8*)&Sx[qr * 64 + ((cc * 8) ^ ((qr & 7) << 3))];
    *(u16x8*)&Ab[(size_t)(b * 2048 + q0 + qh * 32 + qr) * 2048 + h * 64 + cc * 8] = val;
  }
}

extern "C" void kernel_launch(void* const* d_in, const int* in_sizes, int n_in,
                              void* d_out, int out_size, void* d_ws, size_t ws_size,
                              hipStream_t stream) {
  const float* x  = (const float*)d_in[0];
  const float* Wq = (const float*)d_in[1];
  const float* bq = (const float*)d_in[2];
  const float* Wk = (const float*)d_in[3];
  const float* bk = (const float*)d_in[4];
  const float* Wv = (const float*)d_in[5];
  const float* bv = (const float*)d_in[6];
  const float* Wo = (const float*)d_in[7];
  const float* bo = (const float*)d_in[8];

  char* ws = (char*)d_ws;
  u16* xb  = (u16*)(ws + 0);          // 4096*2048 bf16 = 16 MiB
  u16* Ab  = (u16*)(ws + 0);          // aliases xb (xb dead after QKV gemm)
  u16* Qb  = (u16*)(ws + 16777216);   // 4096*2048
  u16* Kb  = (u16*)(ws + 33554432);   // 4096*512
  u16* Vb  = (u16*)(ws + 37748736);   // 4096*512
  u16* Wqt = (u16*)(ws + 41943040);   // 2048*2048
  u16* Wkt = (u16*)(ws + 50331648);   // 512*2048
  u16* Wvt = (u16*)(ws + 52428800);   // 512*2048
  u16* Wot = (u16*)(ws + 54525952);   // 2048*2048

  cvt_kernel<<<8192, 256, 0, stream>>>(x, xb, 2 * 2048 * 2048);
  cvt_t_all_kernel<<<dim3(160, 64), 256, 0, stream>>>(Wq, Wk, Wv, Wo, Wqt, Wkt, Wvt, Wot);

  qkv_gemm_kernel<<<dim3(24, 32), 512, 0, stream>>>(xb, Wqt, Wkt, Wvt, bq, bk, bv, Qb, Kb, Vb);
  attn_kernel<<<dim3(512), 512, 0, stream>>>(Qb, Kb, Vb, Ab);
  oproj_kernel<<<dim3(16, 32), 512, 0, stream>>>(Ab, Wot, bo, (float*)d_out);
}